// Round 11
// baseline (4786.419 us; speedup 1.0000x reference)
//
#include <hip/hip_runtime.h>
#include <math.h>

#define FEAT 1024
#define NB 16       // batch
#define NT 256      // seq len
#define VOCAB 32000
#define G3 3072     // 3*FEAT
#define NWG 256     // scan workgroups
#define FLAG_STRIDE 32   // 128B between flags -> spread across LLC slices
#define NGRP 8      // barrier groups
#define GSZ 32      // blocks per group

#define BK 32       // K-step of the MFMA GEMM
#define LDH 40      // f16 row stride in LDS

typedef float f4 __attribute__((ext_vector_type(4)));
typedef float f32x4 __attribute__((ext_vector_type(4)));
typedef _Float16 half4v __attribute__((ext_vector_type(4)));
typedef _Float16 half8v __attribute__((ext_vector_type(8)));

// ---------------- embedding gather: xs[t*NB+b][:] = emb[x[b][t]] ----------------
__global__ __launch_bounds__(256) void gather_kernel(const int* __restrict__ x,
                                                     const float* __restrict__ emb,
                                                     float* __restrict__ xs) {
    int row = blockIdx.x;
    int t = row >> 4;
    int b = row & 15;
    int tok = x[b * NT + t];
    const float4* src = (const float4*)(emb + (size_t)tok * FEAT);
    float4* dst = (float4*)(xs + (size_t)row * FEAT);
    dst[threadIdx.x] = src[threadIdx.x];
}

// ---------------- split-f16 MFMA GEMM (unchanged, passing since round 6) --------
__global__ __launch_bounds__(256, 2) void gemm_split16(
        const float* __restrict__ A, const float* __restrict__ Bm,
        const float* __restrict__ bias, float* __restrict__ C,
        int M, int N, int K, int GM, int perm) {
    __shared__ _Float16 AhS[128 * LDH];
    __shared__ _Float16 AlS[128 * LDH];
    __shared__ _Float16 BhS[128 * LDH];
    __shared__ _Float16 BlS[128 * LDH];

    int nNt = N >> 7;
    int perGroup = GM * nNt;
    int g = blockIdx.x / perGroup;
    int rix = blockIdx.x % perGroup;
    int n_t = rix / GM;
    int m_t = g * GM + (rix % GM);

    int tid = threadIdx.x;
    int srow = tid >> 1;
    int shf = tid & 1;

    const float* aptr = A + (size_t)(m_t * 128 + srow) * K + shf * 16;
    const float* bptr = Bm + (size_t)(n_t * 128 + srow) * K + shf * 16;

    int wid = tid >> 6;
    int wr = wid >> 1, wc = wid & 1;
    int lane = tid & 63;
    int fr = lane & 15;
    int ke = lane >> 4;

    f32x4 acc[4][4];
#pragma unroll
    for (int i = 0; i < 4; i++)
#pragma unroll
        for (int j = 0; j < 4; j++) acc[i][j] = (f32x4){0.f, 0.f, 0.f, 0.f};

    float4 a4[4], b4[4];
#pragma unroll
    for (int q = 0; q < 4; q++) {
        a4[q] = *(const float4*)(aptr + q * 4);
        b4[q] = *(const float4*)(bptr + q * 4);
    }

    for (int k0 = 0; k0 < K; k0 += BK) {
        __syncthreads();
#pragma unroll
        for (int q = 0; q < 4; q++) {
            half4v hh, hl;
            hh.x = (_Float16)a4[q].x; hl.x = (_Float16)(a4[q].x - (float)hh.x);
            hh.y = (_Float16)a4[q].y; hl.y = (_Float16)(a4[q].y - (float)hh.y);
            hh.z = (_Float16)a4[q].z; hl.z = (_Float16)(a4[q].z - (float)hh.z);
            hh.w = (_Float16)a4[q].w; hl.w = (_Float16)(a4[q].w - (float)hh.w);
            int o = srow * LDH + shf * 16 + q * 4;
            *(half4v*)&AhS[o] = hh;
            *(half4v*)&AlS[o] = hl;
            half4v gh, gl;
            gh.x = (_Float16)b4[q].x; gl.x = (_Float16)(b4[q].x - (float)gh.x);
            gh.y = (_Float16)b4[q].y; gl.y = (_Float16)(b4[q].y - (float)gh.y);
            gh.z = (_Float16)b4[q].z; gl.z = (_Float16)(b4[q].z - (float)gh.z);
            gh.w = (_Float16)b4[q].w; gl.w = (_Float16)(b4[q].w - (float)gh.w);
            *(half4v*)&BhS[o] = gh;
            *(half4v*)&BlS[o] = gl;
        }
        __syncthreads();

        if (k0 + BK < K) {
#pragma unroll
            for (int q = 0; q < 4; q++) {
                a4[q] = *(const float4*)(aptr + k0 + BK + q * 4);
                b4[q] = *(const float4*)(bptr + k0 + BK + q * 4);
            }
        }

        half8v ah[4], al[4], bh[4], bl[4];
#pragma unroll
        for (int i = 0; i < 4; i++) {
            int ao = (wr * 64 + i * 16 + fr) * LDH + ke * 8;
            ah[i] = *(const half8v*)&AhS[ao];
            al[i] = *(const half8v*)&AlS[ao];
            int bo = (wc * 64 + i * 16 + fr) * LDH + ke * 8;
            bh[i] = *(const half8v*)&BhS[bo];
            bl[i] = *(const half8v*)&BlS[bo];
        }
#pragma unroll
        for (int i = 0; i < 4; i++)
#pragma unroll
            for (int j = 0; j < 4; j++) {
                acc[i][j] = __builtin_amdgcn_mfma_f32_16x16x32_f16(ah[i], bh[j], acc[i][j], 0, 0, 0);
                acc[i][j] = __builtin_amdgcn_mfma_f32_16x16x32_f16(ah[i], bl[j], acc[i][j], 0, 0, 0);
                acc[i][j] = __builtin_amdgcn_mfma_f32_16x16x32_f16(al[i], bh[j], acc[i][j], 0, 0, 0);
            }
    }

#pragma unroll
    for (int j = 0; j < 4; j++) {
        int col = n_t * 128 + wc * 64 + j * 16 + fr;
        float bv = bias[col];
#pragma unroll
        for (int i = 0; i < 4; i++) {
#pragma unroll
            for (int v = 0; v < 4; v++) {
                int mrow = m_t * 128 + wr * 64 + i * 16 + 4 * ke + v;
                int orow = perm ? (((mrow & 15) << 8) | (mrow >> 4)) : mrow;
                C[(size_t)orow * N + col] = acc[i][j][v] + bv;
            }
        }
    }
}

// ---------------- agent-coherent store (bypass non-coherent L2, hit LLC) --------
__device__ __forceinline__ void store_f32_sc(float* p, float v) {
    asm volatile("global_store_dword %0, %1, off sc0 sc1" :: "v"(p), "v"(v) : "memory");
}

// ================= fused two-layer pipelined GRU scan =================
// 257 global steps s: layer0 computes t=s (s<256), layer1 computes t=s-1 (s>=1).
// ONE barrier per s (256 total) instead of 512 + separate xp1 GEMM.
// Inputs per step: v01 = ys0[s-1] (feeds L0-hh AND L1-ih -- same vector!),
//                  v1  = ys1[s-2] (feeds L1-hh).
// W_hh0/W_hh1 LDS-resident (96KB, stride 1024 = conflict-free for kc-consecutive
// f4 reads); W_ih1 via coalesced plain global loads (48KB/CU hot in L2).
// Reduce: xor-1 shuffle pre-reduce -> red[256][33] (34KB). LDS total ~134KB.
// Barrier: hierarchical 2-hop with ROTATING leaders (kills leader-skew tax).
__global__ __launch_bounds__(256, 1) void gru_fused(
        const float* __restrict__ xp0,
        const float* __restrict__ Whh0, const float* __restrict__ bhh0,
        const float* __restrict__ Wih1, const float* __restrict__ bih1,
        const float* __restrict__ Whh1, const float* __restrict__ bhh1,
        const float* __restrict__ h0all,
        float* __restrict__ ys0, float* __restrict__ ys1,
        float* __restrict__ hid,
        unsigned* __restrict__ flags, unsigned* __restrict__ gflags) {
    __shared__ float wl0[12 * 1024];        // W_hh0 rows (gate*4+jl)
    __shared__ float wl1[12 * 1024];        // W_hh1 rows
    __shared__ float red[256 * 33];         // pre-reduced partials
    __shared__ float sumA[256];             // final sums (L0 uses 192, L1 256)

    int wg = blockIdx.x;
    int j0 = wg * 4;
    int tid = threadIdx.x;

    // stage W_hh0 / W_hh1 (coalesced f4)
    for (int rr = 0; rr < 12; rr++) {
        int gate = rr >> 2, jloc = rr & 3;
        int grow = gate * FEAT + j0 + jloc;
        *(float4*)(wl0 + rr * 1024 + tid * 4) =
            ((const float4*)(Whh0 + (size_t)grow * FEAT))[tid];
        *(float4*)(wl1 + rr * 1024 + tid * 4) =
            ((const float4*)(Whh1 + (size_t)grow * FEAT))[tid];
    }
    __syncthreads();

    int bg = tid >> 6;        // 0..3 batch group
    int kc = tid & 63;        // 0..63 k chunk
    int pb = tid >> 2, pjl = tid & 3, pj = j0 + pjl;   // gating map (tid<64)

    // gating registers
    float xr = 0.f, xz = 0.f, xnv = 0.f;
    float hreg0 = 0.f, hreg1 = 0.f;
    float b0r = 0.f, b0z = 0.f, b0n = 0.f;
    float bi1r = 0.f, bi1z = 0.f, bi1n = 0.f;
    float bh1r = 0.f, bh1z = 0.f, bh1n = 0.f;
    if (tid < 64) {
        const float* xpr = xp0 + (size_t)(0 * NB + pb) * G3;
        xr = xpr[pj]; xz = xpr[FEAT + pj]; xnv = xpr[2 * FEAT + pj];
        hreg0 = h0all[pb * FEAT + pj];
        hreg1 = h0all[NB * FEAT + pb * FEAT + pj];
        b0r = bhh0[pj]; b0z = bhh0[FEAT + pj]; b0n = bhh0[2 * FEAT + pj];
        bi1r = bih1[pj]; bi1z = bih1[FEAT + pj]; bi1n = bih1[2 * FEAT + pj];
        bh1r = bhh1[pj]; bh1z = bhh1[FEAT + pj]; bh1n = bhh1[2 * FEAT + pj];
    }

    const float* wih_r = Wih1 + (size_t)(0 * FEAT) * FEAT;
    const float* wih_z = Wih1 + (size_t)(1 * FEAT) * FEAT;
    const float* wih_n = Wih1 + (size_t)(2 * FEAT) * FEAT;

    for (int s = 0; s <= NT; s++) {
        // ---- input vectors (plain cached loads; ring addresses are virgin) ----
        const float* v01src = (s == 0) ? h0all
                                       : (ys0 + (size_t)(s - 1) * NB * FEAT);
        f4 v01[16];   // [bi*4+q]
#pragma unroll
        for (int bi = 0; bi < 4; bi++) {
            const float* p = v01src + (size_t)(bg * 4 + bi) * FEAT + kc * 4;
#pragma unroll
            for (int q = 0; q < 4; q++) v01[bi * 4 + q] = *(const f4*)(p + q * 256);
        }
        f4 v1[16];
        if (s >= 1) {
            const float* v1src = (s == 1) ? (h0all + NB * FEAT)
                                          : (ys1 + (size_t)(s - 2) * NB * FEAT);
#pragma unroll
            for (int bi = 0; bi < 4; bi++) {
                const float* p = v1src + (size_t)(bg * 4 + bi) * FEAT + kc * 4;
#pragma unroll
                for (int q = 0; q < 4; q++) v1[bi * 4 + q] = *(const f4*)(p + q * 256);
            }
        }

        // ================= layer 0: h0(s) =================
        if (s < NT) {
            float part[48];
#pragma unroll
            for (int i = 0; i < 48; i++) part[i] = 0.f;
#pragma unroll
            for (int q = 0; q < 4; q++) {
                int kof = q * 256 + kc * 4;
#pragma unroll
                for (int rr = 0; rr < 12; rr++) {
                    f4 w = *(const f4*)&wl0[rr * 1024 + kof];
#pragma unroll
                    for (int bi = 0; bi < 4; bi++) {
                        f4 h = v01[bi * 4 + q];
                        float p = part[rr * 4 + bi];
                        p = fmaf(h.x, w.x, p); p = fmaf(h.y, w.y, p);
                        p = fmaf(h.z, w.z, p); p = fmaf(h.w, w.w, p);
                        part[rr * 4 + bi] = p;
                    }
                }
            }
#pragma unroll
            for (int i = 0; i < 48; i++) part[i] += __shfl_xor(part[i], 1);
            if ((kc & 1) == 0) {
#pragma unroll
                for (int rr = 0; rr < 12; rr++)
#pragma unroll
                    for (int bi = 0; bi < 4; bi++)
                        red[(rr * 16 + bg * 4 + bi) * 33 + (kc >> 1)] =
                            part[rr * 4 + bi];
            }
        }
        __syncthreads();
        if (s < NT && tid < 192) {
            float t0 = 0.f;
#pragma unroll
            for (int c = 0; c < 32; c++) t0 += red[tid * 33 + c];
            sumA[tid] = t0;
        }
        __syncthreads();
        if (s < NT && tid < 64) {
            float dr = sumA[pjl * 16 + pb] + b0r;
            float dz = sumA[(4 + pjl) * 16 + pb] + b0z;
            float dn = sumA[(8 + pjl) * 16 + pb] + b0n;
            float r = 1.f / (1.f + expf(-(xr + dr)));
            float z = 1.f / (1.f + expf(-(xz + dz)));
            float n = tanhf(xnv + r * dn);
            float hv = (1.f - z) * n + z * hreg0;
            hreg0 = hv;
            store_f32_sc(ys0 + (size_t)(s * NB + pb) * FEAT + pj, hv);
            if (s == NT - 1) hid[pb * FEAT + pj] = hv;
        }

        // ================= layer 1: h1(s-1) =================
        if (s >= 1) {
            // slots: 0-3 merged-r(jl), 4-7 merged-z, 8-11 ih-n, 12-15 hh-n
            float p1[64];
#pragma unroll
            for (int i = 0; i < 64; i++) p1[i] = 0.f;
#pragma unroll
            for (int q = 0; q < 4; q++) {
                int kof = q * 256 + kc * 4;
#pragma unroll
                for (int jl = 0; jl < 4; jl++) {
                    f4 wir = *(const f4*)(wih_r + (size_t)(j0 + jl) * FEAT + kof);
                    f4 wiz = *(const f4*)(wih_z + (size_t)(j0 + jl) * FEAT + kof);
                    f4 win = *(const f4*)(wih_n + (size_t)(j0 + jl) * FEAT + kof);
                    f4 whr = *(const f4*)&wl1[(0 + jl) * 1024 + kof];
                    f4 whz = *(const f4*)&wl1[(4 + jl) * 1024 + kof];
                    f4 whn = *(const f4*)&wl1[(8 + jl) * 1024 + kof];
#pragma unroll
                    for (int bi = 0; bi < 4; bi++) {
                        f4 a = v01[bi * 4 + q];   // ys0[s-1] (ih input)
                        f4 b = v1[bi * 4 + q];    // h1(s-2)  (hh input)
                        float pr = p1[(jl) * 4 + bi];
                        pr = fmaf(a.x, wir.x, pr); pr = fmaf(a.y, wir.y, pr);
                        pr = fmaf(a.z, wir.z, pr); pr = fmaf(a.w, wir.w, pr);
                        pr = fmaf(b.x, whr.x, pr); pr = fmaf(b.y, whr.y, pr);
                        pr = fmaf(b.z, whr.z, pr); pr = fmaf(b.w, whr.w, pr);
                        p1[(jl) * 4 + bi] = pr;
                        float pz = p1[(4 + jl) * 4 + bi];
                        pz = fmaf(a.x, wiz.x, pz); pz = fmaf(a.y, wiz.y, pz);
                        pz = fmaf(a.z, wiz.z, pz); pz = fmaf(a.w, wiz.w, pz);
                        pz = fmaf(b.x, whz.x, pz); pz = fmaf(b.y, whz.y, pz);
                        pz = fmaf(b.z, whz.z, pz); pz = fmaf(b.w, whz.w, pz);
                        p1[(4 + jl) * 4 + bi] = pz;
                        float pn = p1[(8 + jl) * 4 + bi];
                        pn = fmaf(a.x, win.x, pn); pn = fmaf(a.y, win.y, pn);
                        pn = fmaf(a.z, win.z, pn); pn = fmaf(a.w, win.w, pn);
                        p1[(8 + jl) * 4 + bi] = pn;
                        float ph = p1[(12 + jl) * 4 + bi];
                        ph = fmaf(b.x, whn.x, ph); ph = fmaf(b.y, whn.y, ph);
                        ph = fmaf(b.z, whn.z, ph); ph = fmaf(b.w, whn.w, ph);
                        p1[(12 + jl) * 4 + bi] = ph;
                    }
                }
            }
#pragma unroll
            for (int i = 0; i < 64; i++) p1[i] += __shfl_xor(p1[i], 1);
            if ((kc & 1) == 0) {
#pragma unroll
                for (int sl = 0; sl < 16; sl++)
#pragma unroll
                    for (int bi = 0; bi < 4; bi++)
                        red[(sl * 16 + bg * 4 + bi) * 33 + (kc >> 1)] =
                            p1[sl * 4 + bi];
            }
        }
        __syncthreads();
        if (s >= 1) {
            float t1 = 0.f;
#pragma unroll
            for (int c = 0; c < 32; c++) t1 += red[tid * 33 + c];
            sumA[tid] = t1;
        }
        __syncthreads();
        if (s >= 1 && tid < 64) {
            float mr = sumA[(0 + pjl) * 16 + pb] + bi1r + bh1r;
            float mz = sumA[(4 + pjl) * 16 + pb] + bi1z + bh1z;
            float in = sumA[(8 + pjl) * 16 + pb] + bi1n;
            float hn = sumA[(12 + pjl) * 16 + pb] + bh1n;
            float r = 1.f / (1.f + expf(-mr));
            float z = 1.f / (1.f + expf(-mz));
            float n = tanhf(in + r * hn);
            float hv = (1.f - z) * n + z * hreg1;
            hreg1 = hv;
            store_f32_sc(ys1 + (size_t)((s - 1) * NB + pb) * FEAT + pj, hv);
            if (s - 1 == NT - 1) hid[NB * FEAT + pb * FEAT + pj] = hv;
        }

        // ================= barrier (skip after final step) =================
        if (s < NT) {
            unsigned expected = (unsigned)(s + 1);
            __syncthreads();
            if (tid == 0) {
                asm volatile("s_waitcnt vmcnt(0)\n\t"
                             "global_store_dword %0, %1, off sc0 sc1"
                             :: "v"(&flags[wg * FLAG_STRIDE]), "v"(expected) : "memory");
            }
            // xp0[s+1] prefetch inside the wait window
            if (tid < 64) {
                int tn = (s + 1 < NT) ? s + 1 : NT - 1;
                const float* xpr = xp0 + (size_t)(tn * NB + pb) * G3;
                xr = xpr[pj]; xz = xpr[FEAT + pj]; xnv = xpr[2 * FEAT + pj];
            }
            // rotating leaders: this step's leaders were idle last step
            int lid = wg - ((s * NGRP) & (NWG - 1));
            if (lid < 0) lid += NWG;
            if (lid < NGRP) {
                if (tid < GSZ) {
                    const unsigned* fp = flags + (lid * GSZ + tid) * FLAG_STRIDE;
                    unsigned v; int spins = 0;
                    while (true) {
                        asm volatile("global_load_dword %0, %1, off sc0 sc1\n\t"
                                     "s_waitcnt vmcnt(0)"
                                     : "=&v"(v) : "v"(fp) : "memory");
                        if (v >= expected) break;
                        if (++spins > (1 << 20)) break;
                        __builtin_amdgcn_s_sleep(1);
                    }
                }
                if (tid == 0) {
                    asm volatile("global_store_dword %0, %1, off sc0 sc1"
                                 :: "v"(&gflags[lid * FLAG_STRIDE]), "v"(expected) : "memory");
                }
            }
            if (tid < NGRP) {
                const unsigned* gp = gflags + tid * FLAG_STRIDE;
                unsigned v; int spins = 0;
                while (true) {
                    asm volatile("global_load_dword %0, %1, off sc0 sc1\n\t"
                                 "s_waitcnt vmcnt(0)"
                                 : "=&v"(v) : "v"(gp) : "memory");
                    if (v >= expected) break;
                    if (++spins > (1 << 20)) break;
                    __builtin_amdgcn_s_sleep(1);
                }
            }
            __builtin_amdgcn_sched_barrier(0);
            __syncthreads();
        }
    }
}

// ---------------- launcher ----------------
extern "C" void kernel_launch(void* const* d_in, const int* in_sizes, int n_in,
                              void* d_out, int out_size, void* d_ws, size_t ws_size,
                              hipStream_t stream) {
    const int*   x     = (const int*)d_in[0];
    const float* h0    = (const float*)d_in[1];
    const float* emb   = (const float*)d_in[2];
    const float* W_ih0 = (const float*)d_in[3];
    const float* W_hh0 = (const float*)d_in[4];
    const float* b_ih0 = (const float*)d_in[5];
    const float* b_hh0 = (const float*)d_in[6];
    const float* W_ih1 = (const float*)d_in[7];
    const float* W_hh1 = (const float*)d_in[8];
    const float* b_ih1 = (const float*)d_in[9];
    const float* b_hh1 = (const float*)d_in[10];
    const float* dec_b = (const float*)d_in[11];

    float* out = (float*)d_out;
    float* hid_out = out + (size_t)NB * NT * VOCAB;

    float* ws  = (float*)d_ws;
    float* xp  = ws;                                    // [4096][3072] (xp0)
    float* xs  = xp + (size_t)4096 * 3072;              // gather out; later ys1 ring
    float* ys0 = xs + (size_t)4096 * 1024;              // [4096][1024] ring
    float* pad = ys0 + (size_t)4096 * 1024;
    unsigned* flags  = (unsigned*)(pad + 2 * NB * FEAT);
    unsigned* gflags = flags + NWG * FLAG_STRIDE;
    float* ys1 = xs;                                    // ring (xs dead after xp0)

    // 0. zero barrier flags
    hipMemsetAsync((void*)flags, 0,
                   (NWG + NGRP) * FLAG_STRIDE * sizeof(unsigned), stream);

    // 1. gather
    gather_kernel<<<dim3(NT * NB), dim3(256), 0, stream>>>(x, emb, xs);

    // 2. x_proj layer 0 (split-f16 MFMA)
    gemm_split16<<<dim3((4096 / 128) * (G3 / 128)), dim3(256), 0, stream>>>(
        xs, W_ih0, b_ih0, xp, 4096, G3, FEAT, 8, 0);

    // 3. fused two-layer pipelined scan (256 barriers)
    gru_fused<<<dim3(NWG), dim3(256), 0, stream>>>(
        xp, W_hh0, b_hh0, W_ih1, b_ih1, W_hh1, b_hh1, h0,
        ys0, ys1, hid_out, flags, gflags);

    // 4. tied decoder (split-f16 MFMA, perm on C-write)
    gemm_split16<<<dim3((4096 / 128) * (VOCAB / 128)), dim3(256), 0, stream>>>(
        ys1, emb, dec_b, out, 4096, VOCAB, FEAT, 8, 1);
}

// Round 13
// 3793.696 us; speedup vs baseline: 1.2617x; 1.2617x over previous
//
#include <hip/hip_runtime.h>
#include <math.h>

#define FEAT 1024
#define NB 16       // batch
#define NT 256      // seq len
#define VOCAB 32000
#define G3 3072     // 3*FEAT
#define NWG 256     // blocks per layer
#define FLAG_STRIDE 32   // 128B between flags
#define NGRP 8
#define GSZ 32

#define BK 32       // K-step of the MFMA GEMM
#define LDH 40      // f16 row stride in LDS

typedef float f4 __attribute__((ext_vector_type(4)));
typedef float f32x4 __attribute__((ext_vector_type(4)));
typedef _Float16 half4v __attribute__((ext_vector_type(4)));
typedef _Float16 half8v __attribute__((ext_vector_type(8)));

// ---------------- embedding gather ----------------
__global__ __launch_bounds__(256) void gather_kernel(const int* __restrict__ x,
                                                     const float* __restrict__ emb,
                                                     float* __restrict__ xs) {
    int row = blockIdx.x;
    int t = row >> 4;
    int b = row & 15;
    int tok = x[b * NT + t];
    const float4* src = (const float4*)(emb + (size_t)tok * FEAT);
    float4* dst = (float4*)(xs + (size_t)row * FEAT);
    dst[threadIdx.x] = src[threadIdx.x];
}

// ---------------- split-f16 MFMA GEMM (verified since round 6) ----------------
__global__ __launch_bounds__(256, 2) void gemm_split16(
        const float* __restrict__ A, const float* __restrict__ Bm,
        const float* __restrict__ bias, float* __restrict__ C,
        int M, int N, int K, int GM, int perm) {
    __shared__ _Float16 AhS[128 * LDH];
    __shared__ _Float16 AlS[128 * LDH];
    __shared__ _Float16 BhS[128 * LDH];
    __shared__ _Float16 BlS[128 * LDH];

    int nNt = N >> 7;
    int perGroup = GM * nNt;
    int g = blockIdx.x / perGroup;
    int rix = blockIdx.x % perGroup;
    int n_t = rix / GM;
    int m_t = g * GM + (rix % GM);

    int tid = threadIdx.x;
    int srow = tid >> 1;
    int shf = tid & 1;

    const float* aptr = A + (size_t)(m_t * 128 + srow) * K + shf * 16;
    const float* bptr = Bm + (size_t)(n_t * 128 + srow) * K + shf * 16;

    int wid = tid >> 6;
    int wr = wid >> 1, wc = wid & 1;
    int lane = tid & 63;
    int fr = lane & 15;
    int ke = lane >> 4;

    f32x4 acc[4][4];
#pragma unroll
    for (int i = 0; i < 4; i++)
#pragma unroll
        for (int j = 0; j < 4; j++) acc[i][j] = (f32x4){0.f, 0.f, 0.f, 0.f};

    float4 a4[4], b4[4];
#pragma unroll
    for (int q = 0; q < 4; q++) {
        a4[q] = *(const float4*)(aptr + q * 4);
        b4[q] = *(const float4*)(bptr + q * 4);
    }

    for (int k0 = 0; k0 < K; k0 += BK) {
        __syncthreads();
#pragma unroll
        for (int q = 0; q < 4; q++) {
            half4v hh, hl;
            hh.x = (_Float16)a4[q].x; hl.x = (_Float16)(a4[q].x - (float)hh.x);
            hh.y = (_Float16)a4[q].y; hl.y = (_Float16)(a4[q].y - (float)hh.y);
            hh.z = (_Float16)a4[q].z; hl.z = (_Float16)(a4[q].z - (float)hh.z);
            hh.w = (_Float16)a4[q].w; hl.w = (_Float16)(a4[q].w - (float)hh.w);
            int o = srow * LDH + shf * 16 + q * 4;
            *(half4v*)&AhS[o] = hh;
            *(half4v*)&AlS[o] = hl;
            half4v gh, gl;
            gh.x = (_Float16)b4[q].x; gl.x = (_Float16)(b4[q].x - (float)gh.x);
            gh.y = (_Float16)b4[q].y; gl.y = (_Float16)(b4[q].y - (float)gh.y);
            gh.z = (_Float16)b4[q].z; gl.z = (_Float16)(b4[q].z - (float)gh.z);
            gh.w = (_Float16)b4[q].w; gl.w = (_Float16)(b4[q].w - (float)gh.w);
            *(half4v*)&BhS[o] = gh;
            *(half4v*)&BlS[o] = gl;
        }
        __syncthreads();

        if (k0 + BK < K) {
#pragma unroll
            for (int q = 0; q < 4; q++) {
                a4[q] = *(const float4*)(aptr + k0 + BK + q * 4);
                b4[q] = *(const float4*)(bptr + k0 + BK + q * 4);
            }
        }

        half8v ah[4], al[4], bh[4], bl[4];
#pragma unroll
        for (int i = 0; i < 4; i++) {
            int ao = (wr * 64 + i * 16 + fr) * LDH + ke * 8;
            ah[i] = *(const half8v*)&AhS[ao];
            al[i] = *(const half8v*)&AlS[ao];
            int bo = (wc * 64 + i * 16 + fr) * LDH + ke * 8;
            bh[i] = *(const half8v*)&BhS[bo];
            bl[i] = *(const half8v*)&BlS[bo];
        }
#pragma unroll
        for (int i = 0; i < 4; i++)
#pragma unroll
            for (int j = 0; j < 4; j++) {
                acc[i][j] = __builtin_amdgcn_mfma_f32_16x16x32_f16(ah[i], bh[j], acc[i][j], 0, 0, 0);
                acc[i][j] = __builtin_amdgcn_mfma_f32_16x16x32_f16(ah[i], bl[j], acc[i][j], 0, 0, 0);
                acc[i][j] = __builtin_amdgcn_mfma_f32_16x16x32_f16(al[i], bh[j], acc[i][j], 0, 0, 0);
            }
    }

#pragma unroll
    for (int j = 0; j < 4; j++) {
        int col = n_t * 128 + wc * 64 + j * 16 + fr;
        float bv = bias[col];
#pragma unroll
        for (int i = 0; i < 4; i++) {
#pragma unroll
            for (int v = 0; v < 4; v++) {
                int mrow = m_t * 128 + wr * 64 + i * 16 + 4 * ke + v;
                int orow = perm ? (((mrow & 15) << 8) | (mrow >> 4)) : mrow;
                C[(size_t)orow * N + col] = acc[i][j][v] + bv;
            }
        }
    }
}

// ---------------- agent-coherent store (LLC) ----------------
__device__ __forceinline__ void store_f32_sc(float* p, float v) {
    asm volatile("global_store_dword %0, %1, off sc0 sc1" :: "v"(p), "v"(v) : "memory");
}

// verified 2-hop barrier building blocks (round 10): sc1 flag store after
// vmcnt(0) drain; leaders poll members (sc0 sc1), post gflag; all poll gflags.
__device__ __forceinline__ void bar_arrive(unsigned* flag, unsigned expected) {
    asm volatile("s_waitcnt vmcnt(0)\n\t"
                 "global_store_dword %0, %1, off sc0 sc1"
                 :: "v"(flag), "v"(expected) : "memory");
}
__device__ __forceinline__ void bar_poll(const unsigned* p, unsigned expected) {
    unsigned v; int spins = 0;
    while (true) {
        asm volatile("global_load_dword %0, %1, off sc0 sc1\n\t"
                     "s_waitcnt vmcnt(0)"
                     : "=&v"(v) : "v"(p) : "memory");
        if (v >= expected) break;
        if (++spins > (1 << 20)) break;   // safety valve
        __builtin_amdgcn_s_sleep(1);
    }
}

// ================= dual-layer concurrent scan =================
// 512 blocks, 2/CU (74KB LDS each). Blocks 0..255 = layer0 (round-10 compute,
// round-11 shuffle reduce). Blocks 256..511 = layer1: per step t, gate on L0's
// gflags >= t+1 (ys0[t] complete), then compute BOTH the ih projection
// (W_ih1 from global, L2-hot) and hh matvec on VALU, publish ys1[t], own
// 2-hop barrier. The two barrier chains overlap in time; L0 never waits on L1.
__global__ __launch_bounds__(256, 2) void gru_dual(
        const float* __restrict__ xp0,
        const float* __restrict__ Whh0, const float* __restrict__ bhh0,
        const float* __restrict__ Wih1, const float* __restrict__ bih1,
        const float* __restrict__ Whh1, const float* __restrict__ bhh1,
        const float* __restrict__ h0all,
        float* __restrict__ ys0, float* __restrict__ ys1,
        float* __restrict__ hid,
        unsigned* __restrict__ flags0, unsigned* __restrict__ gflags0,
        unsigned* __restrict__ flags1, unsigned* __restrict__ gflags1) {
    __shared__ float w_lds[12 * 1028];      // 49.3 KB (layer's own W_hh)
    __shared__ float red[192 * 33];         // 25.3 KB (L1 uses 256*17 <= this)
    __shared__ float sums[256];
    __shared__ float bhh_lds[12];

    int bid = blockIdx.x;
    int isL1 = bid >= NWG;
    int wg = bid & (NWG - 1);
    int j0 = wg * 4;
    int tid = threadIdx.x;

    const float* Whh = isL1 ? Whh1 : Whh0;
    for (int rr = 0; rr < 12; rr++) {
        int gate = rr >> 2, jloc = rr & 3;
        int grow = gate * FEAT + j0 + jloc;
        float4 v = ((const float4*)(Whh + (size_t)grow * FEAT))[tid];
        *(float4*)(w_lds + rr * 1028 + tid * 4) = v;
    }
    if (!isL1 && tid < 12) {
        int gate = tid >> 2, jloc = tid & 3;
        bhh_lds[tid] = bhh0[gate * FEAT + j0 + jloc];
    }
    __syncthreads();

    int bg = tid >> 6;        // 0..3 batch group
    int kc = tid & 63;        // 0..63 k chunk
    int pb = tid >> 2, pjl = tid & 3, pj = j0 + pjl;   // gating map (tid<64)

    if (!isL1) {
        // ======================= LAYER 0 (round-10 verified) =======================
        float xr = 0.f, xz = 0.f, xnv = 0.f, hreg = 0.f;
        if (tid < 64) {
            const float* xpr = xp0 + (size_t)(0 * NB + pb) * G3;
            xr = xpr[pj]; xz = xpr[FEAT + pj]; xnv = xpr[2 * FEAT + pj];
            hreg = h0all[pb * FEAT + pj];
        }
        for (int t = 0; t < NT; t++) {
            const float* hc = (t == 0) ? h0all : (ys0 + (size_t)(t - 1) * NB * FEAT);
            f4 h4[16];
#pragma unroll
            for (int bi = 0; bi < 4; bi++) {
                const float* hp = hc + (size_t)(bg * 4 + bi) * FEAT + kc * 4;
#pragma unroll
                for (int q = 0; q < 4; q++)
                    h4[bi * 4 + q] = *(const f4*)(hp + q * 256);
            }
            float part[48];
#pragma unroll
            for (int i = 0; i < 48; i++) part[i] = 0.f;
#pragma unroll
            for (int q = 0; q < 4; q++) {
                int kof = q * 256 + kc * 4;
#pragma unroll
                for (int rr = 0; rr < 12; rr++) {
                    f4 w = *(const f4*)&w_lds[rr * 1028 + kof];
#pragma unroll
                    for (int bi = 0; bi < 4; bi++) {
                        f4 h = h4[bi * 4 + q];
                        float p = part[rr * 4 + bi];
                        p = fmaf(h.x, w.x, p); p = fmaf(h.y, w.y, p);
                        p = fmaf(h.z, w.z, p); p = fmaf(h.w, w.w, p);
                        part[rr * 4 + bi] = p;
                    }
                }
            }
#pragma unroll
            for (int i = 0; i < 48; i++) part[i] += __shfl_xor(part[i], 1);
            if ((kc & 1) == 0) {
#pragma unroll
                for (int rr = 0; rr < 12; rr++)
#pragma unroll
                    for (int bi = 0; bi < 4; bi++)
                        red[(rr * 16 + bg * 4 + bi) * 33 + (kc >> 1)] = part[rr * 4 + bi];
            }
            __syncthreads();
            if (tid < 192) {
                float s = 0.f;
#pragma unroll
                for (int c = 0; c < 32; c++) s += red[tid * 33 + c];
                sums[tid] = s;
            }
            __syncthreads();
            if (tid < 64) {
                float dr = sums[pjl * 16 + pb] + bhh_lds[pjl];
                float dz = sums[(4 + pjl) * 16 + pb] + bhh_lds[4 + pjl];
                float dn = sums[(8 + pjl) * 16 + pb] + bhh_lds[8 + pjl];
                float r = 1.f / (1.f + expf(-(xr + dr)));
                float z = 1.f / (1.f + expf(-(xz + dz)));
                float n = tanhf(xnv + r * dn);
                float hv = (1.f - z) * n + z * hreg;
                hreg = hv;
                store_f32_sc(ys0 + (size_t)(t * NB + pb) * FEAT + pj, hv);
                if (t == NT - 1) hid[pb * FEAT + pj] = hv;
            }
            // -------- L0 barrier (round-10 verified) --------
            unsigned expected = (unsigned)(t + 1);
            __syncthreads();
            if (tid == 0) bar_arrive(&flags0[wg * FLAG_STRIDE], expected);
            if (tid < 64) {
                int tn = (t + 1 < NT) ? t + 1 : t;
                const float* xpr = xp0 + (size_t)(tn * NB + pb) * G3;
                xr = xpr[pj]; xz = xpr[FEAT + pj]; xnv = xpr[2 * FEAT + pj];
            }
            if (wg < NGRP) {
                if (tid < GSZ) bar_poll(flags0 + (wg * GSZ + tid) * FLAG_STRIDE, expected);
                if (tid == 0) {
                    asm volatile("global_store_dword %0, %1, off sc0 sc1"
                                 :: "v"(&gflags0[wg * FLAG_STRIDE]), "v"(expected) : "memory");
                }
            }
            if (tid < NGRP) bar_poll(gflags0 + tid * FLAG_STRIDE, expected);
            __builtin_amdgcn_sched_barrier(0);
            __syncthreads();
        }
    } else {
        // ======================= LAYER 1 =======================
        float hreg = 0.f;
        float bi1r = 0.f, bi1z = 0.f, bi1n = 0.f, bh1r = 0.f, bh1z = 0.f, bh1n = 0.f;
        if (tid < 64) {
            hreg = h0all[NB * FEAT + pb * FEAT + pj];
            bi1r = bih1[pj]; bi1z = bih1[FEAT + pj]; bi1n = bih1[2 * FEAT + pj];
            bh1r = bhh1[pj]; bh1z = bhh1[FEAT + pj]; bh1n = bhh1[2 * FEAT + pj];
        }
        // constant W_ih1 row bases for this block's 4 columns
        const float* wihr[4]; const float* wihz[4]; const float* wihn[4];
#pragma unroll
        for (int jl = 0; jl < 4; jl++) {
            wihr[jl] = Wih1 + (size_t)(0 * FEAT + j0 + jl) * FEAT;
            wihz[jl] = Wih1 + (size_t)(1 * FEAT + j0 + jl) * FEAT;
            wihn[jl] = Wih1 + (size_t)(2 * FEAT + j0 + jl) * FEAT;
        }

        for (int t = 0; t < NT; t++) {
            // gate on L0 progress: ys0[t] fully published <=> all gflags0 >= t+1
            if (tid < NGRP) bar_poll(gflags0 + tid * FLAG_STRIDE, (unsigned)(t + 1));
            __builtin_amdgcn_sched_barrier(0);
            __syncthreads();

            const float* asrc = ys0 + (size_t)t * NB * FEAT;           // ih input
            const float* bsrc = (t == 0) ? (h0all + NB * FEAT)
                                         : (ys1 + (size_t)(t - 1) * NB * FEAT);
            // slots: 0-3 r-merged(jl), 4-7 z-merged, 8-11 ih-n, 12-15 hh-n
            float p1[64];
#pragma unroll
            for (int i = 0; i < 64; i++) p1[i] = 0.f;
#pragma unroll
            for (int q = 0; q < 4; q++) {
                int kof = q * 256 + kc * 4;
                f4 aq[4], bq[4];
#pragma unroll
                for (int bi = 0; bi < 4; bi++) {
                    aq[bi] = *(const f4*)(asrc + (size_t)(bg * 4 + bi) * FEAT + kof);
                    bq[bi] = *(const f4*)(bsrc + (size_t)(bg * 4 + bi) * FEAT + kof);
                }
#pragma unroll
                for (int jl = 0; jl < 4; jl++) {
                    f4 wir = *(const f4*)(wihr[jl] + kof);
                    f4 wiz = *(const f4*)(wihz[jl] + kof);
                    f4 win = *(const f4*)(wihn[jl] + kof);
                    f4 whr = *(const f4*)&w_lds[(0 + jl) * 1028 + kof];
                    f4 whz = *(const f4*)&w_lds[(4 + jl) * 1028 + kof];
                    f4 whn = *(const f4*)&w_lds[(8 + jl) * 1028 + kof];
#pragma unroll
                    for (int bi = 0; bi < 4; bi++) {
                        f4 a = aq[bi], b = bq[bi];
                        float pr = p1[jl * 4 + bi];
                        pr = fmaf(a.x, wir.x, pr); pr = fmaf(a.y, wir.y, pr);
                        pr = fmaf(a.z, wir.z, pr); pr = fmaf(a.w, wir.w, pr);
                        pr = fmaf(b.x, whr.x, pr); pr = fmaf(b.y, whr.y, pr);
                        pr = fmaf(b.z, whr.z, pr); pr = fmaf(b.w, whr.w, pr);
                        p1[jl * 4 + bi] = pr;
                        float pz = p1[(4 + jl) * 4 + bi];
                        pz = fmaf(a.x, wiz.x, pz); pz = fmaf(a.y, wiz.y, pz);
                        pz = fmaf(a.z, wiz.z, pz); pz = fmaf(a.w, wiz.w, pz);
                        pz = fmaf(b.x, whz.x, pz); pz = fmaf(b.y, whz.y, pz);
                        pz = fmaf(b.z, whz.z, pz); pz = fmaf(b.w, whz.w, pz);
                        p1[(4 + jl) * 4 + bi] = pz;
                        float pn = p1[(8 + jl) * 4 + bi];
                        pn = fmaf(a.x, win.x, pn); pn = fmaf(a.y, win.y, pn);
                        pn = fmaf(a.z, win.z, pn); pn = fmaf(a.w, win.w, pn);
                        p1[(8 + jl) * 4 + bi] = pn;
                        float ph = p1[(12 + jl) * 4 + bi];
                        ph = fmaf(b.x, whn.x, ph); ph = fmaf(b.y, whn.y, ph);
                        ph = fmaf(b.z, whn.z, ph); ph = fmaf(b.w, whn.w, ph);
                        p1[(12 + jl) * 4 + bi] = ph;
                    }
                }
            }
#pragma unroll
            for (int i = 0; i < 64; i++) {
                p1[i] += __shfl_xor(p1[i], 1);
                p1[i] += __shfl_xor(p1[i], 2);
            }
            if ((kc & 3) == 0) {
#pragma unroll
                for (int sl = 0; sl < 16; sl++)
#pragma unroll
                    for (int bi = 0; bi < 4; bi++)
                        red[(sl * 16 + bg * 4 + bi) * 17 + (kc >> 2)] = p1[sl * 4 + bi];
            }
            __syncthreads();
            {
                float s = 0.f;
#pragma unroll
                for (int c = 0; c < 16; c++) s += red[tid * 17 + c];
                sums[tid] = s;
            }
            __syncthreads();
            if (tid < 64) {
                float mr = sums[(0 + pjl) * 16 + pb] + bi1r + bh1r;
                float mz = sums[(4 + pjl) * 16 + pb] + bi1z + bh1z;
                float in = sums[(8 + pjl) * 16 + pb] + bi1n;
                float hn = sums[(12 + pjl) * 16 + pb] + bh1n;
                float r = 1.f / (1.f + expf(-mr));
                float z = 1.f / (1.f + expf(-mz));
                float n = tanhf(in + r * hn);
                float hv = (1.f - z) * n + z * hreg;
                hreg = hv;
                store_f32_sc(ys1 + (size_t)(t * NB + pb) * FEAT + pj, hv);
                if (t == NT - 1) hid[NB * FEAT + pb * FEAT + pj] = hv;
            }
            // -------- L1 barrier (same verified structure, private flags) --------
            unsigned expected = (unsigned)(t + 1);
            __syncthreads();
            if (tid == 0) bar_arrive(&flags1[wg * FLAG_STRIDE], expected);
            if (wg < NGRP) {
                if (tid < GSZ) bar_poll(flags1 + (wg * GSZ + tid) * FLAG_STRIDE, expected);
                if (tid == 0) {
                    asm volatile("global_store_dword %0, %1, off sc0 sc1"
                                 :: "v"(&gflags1[wg * FLAG_STRIDE]), "v"(expected) : "memory");
                }
            }
            if (tid < NGRP) bar_poll(gflags1 + tid * FLAG_STRIDE, expected);
            __builtin_amdgcn_sched_barrier(0);
            __syncthreads();
        }
    }
}

// ---------------- launcher ----------------
extern "C" void kernel_launch(void* const* d_in, const int* in_sizes, int n_in,
                              void* d_out, int out_size, void* d_ws, size_t ws_size,
                              hipStream_t stream) {
    const int*   x     = (const int*)d_in[0];
    const float* h0    = (const float*)d_in[1];
    const float* emb   = (const float*)d_in[2];
    const float* W_ih0 = (const float*)d_in[3];
    const float* W_hh0 = (const float*)d_in[4];
    const float* b_ih0 = (const float*)d_in[5];
    const float* b_hh0 = (const float*)d_in[6];
    const float* W_ih1 = (const float*)d_in[7];
    const float* W_hh1 = (const float*)d_in[8];
    const float* b_ih1 = (const float*)d_in[9];
    const float* b_hh1 = (const float*)d_in[10];
    const float* dec_b = (const float*)d_in[11];

    float* out = (float*)d_out;
    float* hid_out = out + (size_t)NB * NT * VOCAB;

    float* ws  = (float*)d_ws;
    float* xp  = ws;                                    // [4096][3072] (xp0)
    float* xs  = xp + (size_t)4096 * 3072;              // gather out; then ys1 ring
    float* ys0 = xs + (size_t)4096 * 1024;              // [4096][1024] ring
    float* pad = ys0 + (size_t)4096 * 1024;
    unsigned* flags0  = (unsigned*)(pad + 2 * NB * FEAT);
    unsigned* gflags0 = flags0 + NWG * FLAG_STRIDE;
    unsigned* flags1  = gflags0 + NGRP * FLAG_STRIDE;
    unsigned* gflags1 = flags1 + NWG * FLAG_STRIDE;
    float* ys1 = xs;                                    // ring (xs dead after xp0)

    // 0. zero all barrier state
    hipMemsetAsync((void*)flags0, 0,
                   (2 * NWG + 2 * NGRP) * FLAG_STRIDE * sizeof(unsigned), stream);

    // 1. gather
    gather_kernel<<<dim3(NT * NB), dim3(256), 0, stream>>>(x, emb, xs);

    // 2. x_proj layer 0 (split-f16 MFMA)
    gemm_split16<<<dim3((4096 / 128) * (G3 / 128)), dim3(256), 0, stream>>>(
        xs, W_ih0, b_ih0, xp, 4096, G3, FEAT, 8, 0);

    // 3. dual-layer concurrent scan (512 blocks, 2/CU)
    gru_dual<<<dim3(2 * NWG), dim3(256), 0, stream>>>(
        xp, W_hh0, b_hh0, W_ih1, b_ih1, W_hh1, b_hh1, h0,
        ys0, ys1, hid_out, flags0, gflags0, flags1, gflags1);

    // 4. tied decoder (split-f16 MFMA, perm on C-write)
    gemm_split16<<<dim3((4096 / 128) * (VOCAB / 128)), dim3(256), 0, stream>>>(
        ys1, emb, dec_b, out, 4096, VOCAB, FEAT, 8, 1);
}

// Round 14
// 3624.659 us; speedup vs baseline: 1.3205x; 1.0466x over previous
//
#include <hip/hip_runtime.h>
#include <math.h>

#define FEAT 1024
#define NB 16       // batch
#define NT 256      // seq len
#define VOCAB 32000
#define G3 3072     // 3*FEAT
#define NWG 256     // scan blocks per layer
#define FLAG_STRIDE 32   // 128B between flags
#define NGRP 8
#define GSZ 32

#define BK 32       // K-step of the MFMA GEMM
#define LDH 40      // f16 row stride in LDS
#define SMEM_BYTES 75584   // scan layout (75.6KB) >= gemm layout (40KB); x2 = 151KB/CU

typedef float f4 __attribute__((ext_vector_type(4)));
typedef float f32x4 __attribute__((ext_vector_type(4)));
typedef _Float16 half4v __attribute__((ext_vector_type(4)));
typedef _Float16 half8v __attribute__((ext_vector_type(8)));

// ---------------- embedding gather ----------------
__global__ __launch_bounds__(256) void gather_kernel(const int* __restrict__ x,
                                                     const float* __restrict__ emb,
                                                     float* __restrict__ xs) {
    int row = blockIdx.x;
    int t = row >> 4;
    int b = row & 15;
    int tok = x[b * NT + t];
    const float4* src = (const float4*)(emb + (size_t)tok * FEAT);
    float4* dst = (float4*)(xs + (size_t)row * FEAT);
    dst[threadIdx.x] = src[threadIdx.x];
}

// ---------------- agent-coherent store (LLC) ----------------
__device__ __forceinline__ void store_f32_sc(float* p, float v) {
    asm volatile("global_store_dword %0, %1, off sc0 sc1" :: "v"(p), "v"(v) : "memory");
}
// verified 2-hop barrier primitives (round 10/13)
__device__ __forceinline__ void bar_arrive(unsigned* flag, unsigned expected) {
    asm volatile("s_waitcnt vmcnt(0)\n\t"
                 "global_store_dword %0, %1, off sc0 sc1"
                 :: "v"(flag), "v"(expected) : "memory");
}
__device__ __forceinline__ void bar_poll(const unsigned* p, unsigned expected) {
    unsigned v; int spins = 0;
    while (true) {
        asm volatile("global_load_dword %0, %1, off sc0 sc1\n\t"
                     "s_waitcnt vmcnt(0)"
                     : "=&v"(v) : "v"(p) : "memory");
        if (v >= expected) break;
        if (++spins > (1 << 20)) break;   // safety valve
        __builtin_amdgcn_s_sleep(1);
    }
}

// ---------------- split-f16 MFMA GEMM tile (verified body, device fn) ----------
// C[128 x 128] tile at (m_t, n_t): C = A*B^T + bias. K = FEAT.
// perm!=0: C row m -> ((m&15)<<8)|(m>>4)
__device__ __forceinline__ void gemm_tile(char* smemraw,
        const float* __restrict__ A, const float* __restrict__ Bm,
        const float* __restrict__ bias, float* __restrict__ C,
        int N, int K, int m_t, int n_t, int perm) {
    _Float16* AhS = (_Float16*)smemraw;
    _Float16* AlS = AhS + 128 * LDH;
    _Float16* BhS = AlS + 128 * LDH;
    _Float16* BlS = BhS + 128 * LDH;

    int tid = threadIdx.x;
    int srow = tid >> 1;
    int shf = tid & 1;

    const float* aptr = A + (size_t)(m_t * 128 + srow) * K + shf * 16;
    const float* bptr = Bm + (size_t)(n_t * 128 + srow) * K + shf * 16;

    int wid = tid >> 6;
    int wr = wid >> 1, wc = wid & 1;
    int lane = tid & 63;
    int fr = lane & 15;
    int ke = lane >> 4;

    f32x4 acc[4][4];
#pragma unroll
    for (int i = 0; i < 4; i++)
#pragma unroll
        for (int j = 0; j < 4; j++) acc[i][j] = (f32x4){0.f, 0.f, 0.f, 0.f};

    float4 a4[4], b4[4];
#pragma unroll
    for (int q = 0; q < 4; q++) {
        a4[q] = *(const float4*)(aptr + q * 4);
        b4[q] = *(const float4*)(bptr + q * 4);
    }

    for (int k0 = 0; k0 < K; k0 += BK) {
        __syncthreads();
#pragma unroll
        for (int q = 0; q < 4; q++) {
            half4v hh, hl;
            hh.x = (_Float16)a4[q].x; hl.x = (_Float16)(a4[q].x - (float)hh.x);
            hh.y = (_Float16)a4[q].y; hl.y = (_Float16)(a4[q].y - (float)hh.y);
            hh.z = (_Float16)a4[q].z; hl.z = (_Float16)(a4[q].z - (float)hh.z);
            hh.w = (_Float16)a4[q].w; hl.w = (_Float16)(a4[q].w - (float)hh.w);
            int o = srow * LDH + shf * 16 + q * 4;
            *(half4v*)&AhS[o] = hh;
            *(half4v*)&AlS[o] = hl;
            half4v gh, gl;
            gh.x = (_Float16)b4[q].x; gl.x = (_Float16)(b4[q].x - (float)gh.x);
            gh.y = (_Float16)b4[q].y; gl.y = (_Float16)(b4[q].y - (float)gh.y);
            gh.z = (_Float16)b4[q].z; gl.z = (_Float16)(b4[q].z - (float)gh.z);
            gh.w = (_Float16)b4[q].w; gl.w = (_Float16)(b4[q].w - (float)gh.w);
            *(half4v*)&BhS[o] = gh;
            *(half4v*)&BlS[o] = gl;
        }
        __syncthreads();

        if (k0 + BK < K) {
#pragma unroll
            for (int q = 0; q < 4; q++) {
                a4[q] = *(const float4*)(aptr + k0 + BK + q * 4);
                b4[q] = *(const float4*)(bptr + k0 + BK + q * 4);
            }
        }

        half8v ah[4], al[4], bh[4], bl[4];
#pragma unroll
        for (int i = 0; i < 4; i++) {
            int ao = (wr * 64 + i * 16 + fr) * LDH + ke * 8;
            ah[i] = *(const half8v*)&AhS[ao];
            al[i] = *(const half8v*)&AlS[ao];
            int bo = (wc * 64 + i * 16 + fr) * LDH + ke * 8;
            bh[i] = *(const half8v*)&BhS[bo];
            bl[i] = *(const half8v*)&BlS[bo];
        }
#pragma unroll
        for (int i = 0; i < 4; i++)
#pragma unroll
            for (int j = 0; j < 4; j++) {
                acc[i][j] = __builtin_amdgcn_mfma_f32_16x16x32_f16(ah[i], bh[j], acc[i][j], 0, 0, 0);
                acc[i][j] = __builtin_amdgcn_mfma_f32_16x16x32_f16(ah[i], bl[j], acc[i][j], 0, 0, 0);
                acc[i][j] = __builtin_amdgcn_mfma_f32_16x16x32_f16(al[i], bh[j], acc[i][j], 0, 0, 0);
            }
    }

#pragma unroll
    for (int j = 0; j < 4; j++) {
        int col = n_t * 128 + wc * 64 + j * 16 + fr;
        float bv = bias[col];
#pragma unroll
        for (int i = 0; i < 4; i++) {
#pragma unroll
            for (int v = 0; v < 4; v++) {
                int mrow = m_t * 128 + wr * 64 + i * 16 + 4 * ke + v;
                int orow = perm ? (((mrow & 15) << 8) | (mrow >> 4)) : mrow;
                C[(size_t)orow * N + col] = acc[i][j][v] + bv;
            }
        }
    }
}

// ---------------- standalone GEMM kernel (xp0; verified since round 6) --------
__global__ __launch_bounds__(256, 2) void gemm_split16(
        const float* __restrict__ A, const float* __restrict__ Bm,
        const float* __restrict__ bias, float* __restrict__ C,
        int N, int K, int GM, int perm) {
    __shared__ __align__(16) char smem[4 * 128 * LDH * 2];
    int nNt = N >> 7;
    int perGroup = GM * nNt;
    int g = blockIdx.x / perGroup;
    int rix = blockIdx.x % perGroup;
    int n_t = rix / GM;
    int m_t = g * GM + (rix % GM);
    gemm_tile(smem, A, Bm, bias, C, N, K, m_t, n_t, perm);
}

// ---------------- persistent scan layer (round-10 verified structure) ----------
// LDS: w (stride 1024, r11-verified) + xor1-shuffle reduce red[192][33]
// (r13-verified) = 75.6KB so a GEMM block can co-reside on the CU.
__device__ __forceinline__ void scan_layer(char* smemraw,
        const float* __restrict__ xp, const float* __restrict__ Whh,
        const float* __restrict__ bhh, const float* __restrict__ h0src,
        float* __restrict__ ys, float* __restrict__ hid,
        unsigned* __restrict__ flags, unsigned* __restrict__ gflags) {
    float* w_lds   = (float*)smemraw;        // 12*1024
    float* red     = w_lds + 12 * 1024;      // 192*33
    float* sums    = red + 192 * 33;         // 256
    float* bhh_lds = sums + 256;             // 12

    int wg = blockIdx.x;
    int j0 = wg * 4;
    int tid = threadIdx.x;

    for (int rr = 0; rr < 12; rr++) {
        int gate = rr >> 2, jloc = rr & 3;
        int grow = gate * FEAT + j0 + jloc;
        float4 v = ((const float4*)(Whh + (size_t)grow * FEAT))[tid];
        *(float4*)(w_lds + rr * 1024 + tid * 4) = v;
    }
    if (tid < 12) {
        int gate = tid >> 2, jloc = tid & 3;
        bhh_lds[tid] = bhh[gate * FEAT + j0 + jloc];
    }
    __syncthreads();

    int bg = tid >> 6;        // 0..3 batch group
    int kc = tid & 63;        // 0..63 k chunk
    int pb = tid >> 2, pjl = tid & 3, pj = j0 + pjl;   // gating map (tid<64)

    float xr = 0.f, xz = 0.f, xnv = 0.f, hreg = 0.f;
    if (tid < 64) {
        const float* xpr = xp + (size_t)(0 * NB + pb) * G3;
        xr = xpr[pj]; xz = xpr[FEAT + pj]; xnv = xpr[2 * FEAT + pj];
        hreg = h0src[pb * FEAT + pj];
    }

    for (int t = 0; t < NT; t++) {
        const float* hc = (t == 0) ? h0src : (ys + (size_t)(t - 1) * NB * FEAT);

        f4 h4[16];
#pragma unroll
        for (int bi = 0; bi < 4; bi++) {
            const float* hp = hc + (size_t)(bg * 4 + bi) * FEAT + kc * 4;
#pragma unroll
            for (int q = 0; q < 4; q++)
                h4[bi * 4 + q] = *(const f4*)(hp + q * 256);
        }

        float part[48];
#pragma unroll
        for (int i = 0; i < 48; i++) part[i] = 0.f;
#pragma unroll
        for (int q = 0; q < 4; q++) {
            int kof = q * 256 + kc * 4;
#pragma unroll
            for (int rr = 0; rr < 12; rr++) {
                f4 w = *(const f4*)&w_lds[rr * 1024 + kof];
#pragma unroll
                for (int bi = 0; bi < 4; bi++) {
                    f4 h = h4[bi * 4 + q];
                    float p = part[rr * 4 + bi];
                    p = fmaf(h.x, w.x, p); p = fmaf(h.y, w.y, p);
                    p = fmaf(h.z, w.z, p); p = fmaf(h.w, w.w, p);
                    part[rr * 4 + bi] = p;
                }
            }
        }
#pragma unroll
        for (int i = 0; i < 48; i++) part[i] += __shfl_xor(part[i], 1);
        if ((kc & 1) == 0) {
#pragma unroll
            for (int rr = 0; rr < 12; rr++)
#pragma unroll
                for (int bi = 0; bi < 4; bi++)
                    red[(rr * 16 + bg * 4 + bi) * 33 + (kc >> 1)] = part[rr * 4 + bi];
        }
        __syncthreads();

        if (tid < 192) {
            float s = 0.f;
#pragma unroll
            for (int c = 0; c < 32; c++) s += red[tid * 33 + c];
            sums[tid] = s;
        }
        __syncthreads();

        if (tid < 64) {
            float dr = sums[pjl * 16 + pb] + bhh_lds[pjl];
            float dz = sums[(4 + pjl) * 16 + pb] + bhh_lds[4 + pjl];
            float dn = sums[(8 + pjl) * 16 + pb] + bhh_lds[8 + pjl];
            float r = 1.f / (1.f + expf(-(xr + dr)));
            float z = 1.f / (1.f + expf(-(xz + dz)));
            float n = tanhf(xnv + r * dn);
            float hv = (1.f - z) * n + z * hreg;
            hreg = hv;
            store_f32_sc(ys + (size_t)(t * NB + pb) * FEAT + pj, hv);
            if (t == NT - 1) hid[pb * FEAT + pj] = hv;
        }

        // -------- 2-hop barrier (round-10 verified) --------
        unsigned expected = (unsigned)(t + 1);
        __syncthreads();
        if (tid == 0) bar_arrive(&flags[wg * FLAG_STRIDE], expected);
        if (tid < 64) {
            int tn = (t + 1 < NT) ? t + 1 : t;
            const float* xpr = xp + (size_t)(tn * NB + pb) * G3;
            xr = xpr[pj]; xz = xpr[FEAT + pj]; xnv = xpr[2 * FEAT + pj];
        }
        if (wg < NGRP) {
            if (tid < GSZ) bar_poll(flags + (wg * GSZ + tid) * FLAG_STRIDE, expected);
            if (tid == 0) {
                asm volatile("global_store_dword %0, %1, off sc0 sc1"
                             :: "v"(&gflags[wg * FLAG_STRIDE]), "v"(expected) : "memory");
            }
        }
        if (tid < NGRP) bar_poll(gflags + tid * FLAG_STRIDE, expected);
        __builtin_amdgcn_sched_barrier(0);
        __syncthreads();
    }
}

// ---------------- phase 1: scan0 (0..255)  ||  xp1 GEMM gated (256..1023) -----
// xp1 writes xp IN PLACE: tile rows [t0*16,(t0+8)*16) are written only after
// gflags0 >= t0+8, i.e. scan0 finished step t0+7 (incl. its prefetch of row
// t0+8) on every block -> those xp rows are dead for scan0. Safe.
__global__ __launch_bounds__(256, 2) void phase1(
        const float* __restrict__ xp, const float* __restrict__ Whh0,
        const float* __restrict__ bhh0, const float* __restrict__ h0,
        float* __restrict__ ys0, float* __restrict__ hid,
        unsigned* __restrict__ flags0, unsigned* __restrict__ gflags0,
        const float* __restrict__ Wih1, const float* __restrict__ bih1,
        float* __restrict__ xpw) {
    __shared__ __align__(16) char smem[SMEM_BYTES];
    if (blockIdx.x < NWG) {
        scan_layer(smem, xp, Whh0, bhh0, h0, ys0, hid, flags0, gflags0);
    } else {
        int bid = blockIdx.x - NWG;       // 0..767 = 4 groups x (24n x 8m)
        int perGroup = 8 * (G3 >> 7);
        int g = bid / perGroup, rix = bid % perGroup;
        int n_t = rix / 8, m_t = g * 8 + (rix % 8);
        unsigned gate = (unsigned)((m_t + 1) * 8);
        if (threadIdx.x < NGRP) bar_poll(gflags0 + threadIdx.x * FLAG_STRIDE, gate);
        __builtin_amdgcn_sched_barrier(0);
        __syncthreads();
        gemm_tile(smem, ys0, Wih1, bih1, xpw, G3, FEAT, m_t, n_t, 0);
    }
}

// ---------------- phase 2: scan1 (0..255)  ||  decoder GEMM gated -------------
__global__ __launch_bounds__(256, 2) void phase2(
        const float* __restrict__ xp, const float* __restrict__ Whh1,
        const float* __restrict__ bhh1, const float* __restrict__ h0b,
        float* __restrict__ ys1, float* __restrict__ hid1,
        unsigned* __restrict__ flags1, unsigned* __restrict__ gflags1,
        const float* __restrict__ emb, const float* __restrict__ dec_b,
        float* __restrict__ out) {
    __shared__ __align__(16) char smem[SMEM_BYTES];
    if (blockIdx.x < NWG) {
        scan_layer(smem, xp, Whh1, bhh1, h0b, ys1, hid1, flags1, gflags1);
    } else {
        int bid = blockIdx.x - NWG;       // 0..7999 = 4 groups x (250n x 8m)
        int perGroup = 8 * (VOCAB >> 7);
        int g = bid / perGroup, rix = bid % perGroup;
        int n_t = rix / 8, m_t = g * 8 + (rix % 8);
        unsigned gate = (unsigned)((m_t + 1) * 8);
        if (threadIdx.x < NGRP) bar_poll(gflags1 + threadIdx.x * FLAG_STRIDE, gate);
        __builtin_amdgcn_sched_barrier(0);
        __syncthreads();
        gemm_tile(smem, ys1, emb, dec_b, out, VOCAB, FEAT, m_t, n_t, 1);
    }
}

// ---------------- launcher ----------------
extern "C" void kernel_launch(void* const* d_in, const int* in_sizes, int n_in,
                              void* d_out, int out_size, void* d_ws, size_t ws_size,
                              hipStream_t stream) {
    const int*   x     = (const int*)d_in[0];
    const float* h0    = (const float*)d_in[1];
    const float* emb   = (const float*)d_in[2];
    const float* W_ih0 = (const float*)d_in[3];
    const float* W_hh0 = (const float*)d_in[4];
    const float* b_ih0 = (const float*)d_in[5];
    const float* b_hh0 = (const float*)d_in[6];
    const float* W_ih1 = (const float*)d_in[7];
    const float* W_hh1 = (const float*)d_in[8];
    const float* b_ih1 = (const float*)d_in[9];
    const float* b_hh1 = (const float*)d_in[10];
    const float* dec_b = (const float*)d_in[11];

    float* out = (float*)d_out;
    float* hid_out = out + (size_t)NB * NT * VOCAB;

    float* ws  = (float*)d_ws;
    float* xp  = ws;                                    // [4096][3072]
    float* xs  = xp + (size_t)4096 * 3072;              // gather out; then ys1 ring
    float* ys0 = xs + (size_t)4096 * 1024;              // [4096][1024] ring
    float* pad = ys0 + (size_t)4096 * 1024;
    unsigned* flags0  = (unsigned*)(pad + 2 * NB * FEAT);
    unsigned* gflags0 = flags0 + NWG * FLAG_STRIDE;
    unsigned* flags1  = gflags0 + NGRP * FLAG_STRIDE;
    unsigned* gflags1 = flags1 + NWG * FLAG_STRIDE;
    float* ys1 = xs;                                    // ring (xs dead after xp0)

    // 0. zero all barrier state
    hipMemsetAsync((void*)flags0, 0,
                   (2 * NWG + 2 * NGRP) * FLAG_STRIDE * sizeof(unsigned), stream);

    // 1. gather
    gather_kernel<<<dim3(NT * NB), dim3(256), 0, stream>>>(x, emb, xs);

    // 2. x_proj layer 0 (standalone MFMA GEMM)
    gemm_split16<<<dim3((4096 / 128) * (G3 / 128)), dim3(256), 0, stream>>>(
        xs, W_ih0, b_ih0, xp, G3, FEAT, 8, 0);

    // 3. phase 1: scan0 || gated xp1 GEMM (in-place xp rewrite)
    phase1<<<dim3(NWG + (4096 / 128) * (G3 / 128)), dim3(256), 0, stream>>>(
        xp, W_hh0, b_hh0, h0, ys0, hid_out, flags0, gflags0, W_ih1, b_ih1, xp);

    // 4. phase 2: scan1 || gated decoder GEMM
    phase2<<<dim3(NWG + (4096 / 128) * (VOCAB / 128)), dim3(256), 0, stream>>>(
        xp, W_hh1, b_hh1, h0 + NB * FEAT, ys1, hid_out + NB * FEAT,
        flags1, gflags1, emb, dec_b, out);
}